// Round 1
// baseline (259.884 us; speedup 1.0000x reference)
//
#include <hip/hip_runtime.h>

#define TOK 8192   // B*S
#define DIM 512    // D
#define NE  32     // experts
#define KTOT (NE * DIM)

#define BM 128
#define BN 128
#define BK 64

typedef float f32x4  __attribute__((ext_vector_type(4)));
typedef float f32x16 __attribute__((ext_vector_type(16)));
typedef short s16x8  __attribute__((ext_vector_type(8)));

typedef const void __attribute__((address_space(1)))* gp1_t;
typedef void __attribute__((address_space(3)))* lp3_t;

__device__ __forceinline__ void gl_lds16(const void* g, void* l) {
    __builtin_amdgcn_global_load_lds((gp1_t)g, (lp3_t)l, 16, 0, 0);
}

// stage one 16KB tile (128 rows x 128B) with 256 threads: 4 rounds of 16B
__device__ __forceinline__ void stage4(const ushort* g, size_t gstride, char* l) {
    gl_lds16(g,               l);
    gl_lds16(g + gstride,     l + 4096);
    gl_lds16(g + 2 * gstride, l + 8192);
    gl_lds16(g + 3 * gstride, l + 12288);
}

__device__ __forceinline__ ushort f2bf(float f) {
    unsigned u = __builtin_bit_cast(unsigned, f);
    unsigned r = (u + 0x7fffu + ((u >> 16) & 1u)) >> 16;
    return (ushort)r;
}

// ---- fused prep: blocks [0,2048) transpose+convert W; [2048,3072) gates+cvt x
__global__ __launch_bounds__(256) void k_prep(const float* __restrict__ w,
                                              ushort* __restrict__ wt,
                                              const float* __restrict__ x,
                                              const float* __restrict__ gw,
                                              const float* __restrict__ gb,
                                              float* __restrict__ G,
                                              ushort* __restrict__ xb) {
    __shared__ __align__(16) char smem[64 * 65 * 4];
    const int bx = blockIdx.x;
    const int tid = threadIdx.x;
    if (bx < 2048) {
        // ---- Wt[f][e*512+d] = bf16(w[e][d][f]), 64x64 tile ----
        float (*tile)[65] = (float(*)[65])smem;
        const int e = bx >> 6;
        const int f0 = ((bx >> 3) & 7) * 64;
        const int d0 = (bx & 7) * 64;
        const int tx = tid & 63, ty = tid >> 6;  // ty 0..3
        const float* we = w + (size_t)e * DIM * DIM;
#pragma unroll
        for (int i = ty; i < 64; i += 4)
            tile[i][tx] = we[(size_t)(d0 + i) * DIM + f0 + tx];
        __syncthreads();
#pragma unroll
        for (int i = ty; i < 64; i += 4)
            wt[(size_t)(f0 + i) * KTOT + e * DIM + d0 + tx] = f2bf(tile[tx][i]);
    } else {
        // ---- gates (8 tokens/block, shfl softmax) + x -> bf16 ----
        float* xs = (float*)smem;
        const int t0 = (bx - 2048) * 8;
        const float* xBase = x + (size_t)t0 * DIM;
#pragma unroll
        for (int k = 0; k < 4; ++k) {
            int i4 = (k * 256 + tid) * 4;
            float4 v = *(const float4*)(xBase + i4);
            xs[i4 + 0] = v.x; xs[i4 + 1] = v.y; xs[i4 + 2] = v.z; xs[i4 + 3] = v.w;
            ushort4 o;
            o.x = f2bf(v.x); o.y = f2bf(v.y); o.z = f2bf(v.z); o.w = f2bf(v.w);
            *(ushort4*)(xb + (size_t)t0 * DIM + i4) = o;
        }
        __syncthreads();
        const int tok = tid >> 5;   // 0..7
        const int e = tid & 31;
        float l = gb[e];
        const float* xr = xs + tok * DIM;
#pragma unroll 8
        for (int d = 0; d < DIM; ++d)
            l += xr[d] * gw[d * NE + e];
        float mx = l;
#pragma unroll
        for (int m = 16; m >= 1; m >>= 1) mx = fmaxf(mx, __shfl_xor(mx, m));
        float ex = expf(l - mx);
        float s = ex;
#pragma unroll
        for (int m = 16; m >= 1; m >>= 1) s += __shfl_xor(s, m);
        G[(size_t)(t0 + tok) * NE + e] = ex / s;
    }
}

// ------------- main GEMM v2: 32x32x16 MFMA, 64x64 wave tiles -------------
// 256 thr (4 waves 2x2), 2 blocks/CU. kt-outer / e-inner (proven pipeline):
// A-fragments register-resident across the 16-expert inner loop (A depends
// only on kt) -> per-iter LDS reads drop from 12 to 8 b128. Gate fold uses
// broadcast f32x4 reads from Gs (row depends only on lane>>5 in the 32x32
// C/D layout: col=lane&31, row=(reg&3)+8*(reg>>2)+4*(lane>>5)).
// LDS XOR-swizzle (R3-proven): LDS[row][c] = Glob[row][c ^ (row&7)].
__global__ __launch_bounds__(256, 2) void k_moe_gemm(const ushort* __restrict__ xb,
                                                     const ushort* __restrict__ wt,
                                                     const float* __restrict__ G,
                                                     float* __restrict__ out0,
                                                     float* __restrict__ out1) {
    __shared__ __align__(16) ushort As[2][BM * BK];   // 2 x 16 KB
    __shared__ __align__(16) ushort Bs[2][BN * BK];   // 2 x 16 KB
    __shared__ float Gs[16][BM];                      // 8 KB

    const int tid = threadIdx.x;
    const int m0 = blockIdx.y * BM;
    const int n0 = blockIdx.x * BN;
    const int e0 = blockIdx.z * 16;
    float* __restrict__ dst = blockIdx.z ? out1 : out0;

    for (int i = tid; i < 16 * BM; i += 256) {
        int e = i >> 7, r = i & 127;
        Gs[e][r] = G[(size_t)(m0 + r) * NE + e0 + e];
    }

    const int lane = tid & 63;
    const int wave = tid >> 6;          // 0..3
    const int wm = (wave & 1) * 64;
    const int wn = (wave >> 1) * 64;
    const int l31 = lane & 31;
    const int hi = lane >> 5;           // 0..1
    const int key = l31 & 7;

    // frag read offsets: row*128 + ((2s+hi)^ (row&7))*16  (row&7 == key)
    int chunkOff[4], rowOffA[2], rowOffB[2];
#pragma unroll
    for (int s = 0; s < 4; ++s) chunkOff[s] = ((2 * s + hi) ^ key) * 16;
#pragma unroll
    for (int i = 0; i < 2; ++i) {
        rowOffA[i] = (wm + i * 32 + l31) * 128;
        rowOffB[i] = (wn + i * 32 + l31) * 128;
    }

    // staging map: 256 thr x 16B = 4KB/round, 4 rounds per 16KB tile
    const int srow = tid >> 3;                       // 0..31 (+32/round)
    const int scol = ((tid & 7) ^ (srow & 7)) * 8;   // swizzled global column
    const ushort* aBase = xb + (size_t)(m0 + srow) * DIM + scol;
    const ushort* bBase = wt + (size_t)(n0 + srow) * KTOT + (size_t)e0 * DIM + scol;
    const int ldsOff = tid * 16;

    f32x16 zv16;
#pragma unroll
    for (int j = 0; j < 16; ++j) zv16[j] = 0.f;
    f32x16 acc[2][2];
#pragma unroll
    for (int i = 0; i < 2; ++i)
#pragma unroll
        for (int j = 0; j < 2; ++j) acc[i][j] = zv16;

    // prologue: stage A(kt=0) -> As[0], B(e=0,kt=0) -> Bs[0]
    stage4(aBase, (size_t)32 * DIM,  (char*)As[0] + ldsOff);
    stage4(bBase, (size_t)32 * KTOT, (char*)Bs[0] + ldsOff);
    __syncthreads();

#pragma unroll 1
    for (int kt = 0; kt < 8; ++kt) {
        // A fragments -> registers, reused for all 16 experts of this kt
        const char* Ab = (const char*)As[kt & 1];
        s16x8 areg[2][4];
#pragma unroll
        for (int mi = 0; mi < 2; ++mi)
#pragma unroll
            for (int s = 0; s < 4; ++s)
                areg[mi][s] = *(const s16x8*)(Ab + rowOffA[mi] + chunkOff[s]);

#pragma unroll 1
        for (int ee = 0; ee < 16; ++ee) {
            // issue next-tile DMA (one ahead); barrier at end publishes it
            const int gn = kt * 16 + ee + 1;
            if (gn < 128) {
                const ushort* bN = bBase + (size_t)(gn & 15) * DIM + (gn >> 4) * BK;
                stage4(bN, (size_t)32 * KTOT, (char*)Bs[gn & 1] + ldsOff);
                if (ee == 15)
                    stage4(aBase + (gn >> 4) * BK, (size_t)32 * DIM,
                           (char*)As[(gn >> 4) & 1] + ldsOff);
            }

            const char* Bb = (const char*)Bs[ee & 1];
            s16x8 breg[2][4];
#pragma unroll
            for (int nj = 0; nj < 2; ++nj)
#pragma unroll
                for (int s = 0; s < 4; ++s)
                    breg[nj][s] = *(const s16x8*)(Bb + rowOffB[nj] + chunkOff[s]);

#pragma unroll
            for (int mi = 0; mi < 2; ++mi) {
                f32x16 p0 = __builtin_amdgcn_mfma_f32_32x32x16_bf16(areg[mi][0], breg[0][0], zv16, 0, 0, 0);
                f32x16 p1 = __builtin_amdgcn_mfma_f32_32x32x16_bf16(areg[mi][0], breg[1][0], zv16, 0, 0, 0);
#pragma unroll
                for (int s = 1; s < 4; ++s) {
                    p0 = __builtin_amdgcn_mfma_f32_32x32x16_bf16(areg[mi][s], breg[0][s], p0, 0, 0, 0);
                    p1 = __builtin_amdgcn_mfma_f32_32x32x16_bf16(areg[mi][s], breg[1][s], p1, 0, 0, 0);
                }
                // fold with per-token gates; Gs reads are 2-address broadcasts
#pragma unroll
                for (int g = 0; g < 4; ++g) {
                    const f32x4 gt = *(const f32x4*)&Gs[ee][wm + mi * 32 + 8 * g + 4 * hi];
#pragma unroll
                    for (int j = 0; j < 4; ++j) {
                        acc[mi][0][4 * g + j] += gt[j] * p0[4 * g + j];
                        acc[mi][1][4 * g + j] += gt[j] * p1[4 * g + j];
                    }
                }
            }
            __syncthreads();   // publishes next buffers; DMA already complete
        }
    }

    // epilogue: C/D layout col=lane&31, row=(reg&3)+8*(reg>>2)+4*hi
#pragma unroll
    for (int mi = 0; mi < 2; ++mi)
#pragma unroll
        for (int nj = 0; nj < 2; ++nj) {
            const int col = n0 + wn + nj * 32 + l31;
#pragma unroll
            for (int g = 0; g < 4; ++g) {
                float* p = dst + (size_t)(m0 + wm + mi * 32 + 8 * g + 4 * hi) * DIM + col;
                p[0 * DIM] = acc[mi][nj][4 * g + 0];
                p[1 * DIM] = acc[mi][nj][4 * g + 1];
                p[2 * DIM] = acc[mi][nj][4 * g + 2];
                p[3 * DIM] = acc[mi][nj][4 * g + 3];
            }
        }
}

// ---- deterministic two-phase sum: out += P (both fully written upstream) ----
__global__ __launch_bounds__(256) void k_reduce(float* __restrict__ out,
                                                const float* __restrict__ P) {
    int i = (blockIdx.x * 256 + threadIdx.x) * 4;
    float4 a = *(const float4*)(out + i);
    float4 b = *(const float4*)(P + i);
    a.x += b.x; a.y += b.y; a.z += b.z; a.w += b.w;
    *(float4*)(out + i) = a;
}

extern "C" void kernel_launch(void* const* d_in, const int* in_sizes, int n_in,
                              void* d_out, int out_size, void* d_ws, size_t ws_size,
                              hipStream_t stream) {
    const float* x  = (const float*)d_in[0];   // [8192][512]
    const float* gw = (const float*)d_in[1];   // [512][32]
    const float* gb = (const float*)d_in[2];   // [32]
    const float* w  = (const float*)d_in[3];   // [32][512][512]
    float* out = (float*)d_out;                // [8192][512] fp32

    char* ws = (char*)d_ws;
    ushort* xb = (ushort*)ws;                            //  0..8 MiB
    ushort* wt = (ushort*)(ws + (8u << 20));             //  8..24 MiB
    float*  G  = (float*)(ws + (24u << 20));             // 24..25 MiB
    float*  P  = (float*)(ws + (25u << 20));             // 25..41 MiB

    k_prep<<<dim3(2048 + TOK / 8), dim3(256), 0, stream>>>(w, wt, x, gw, gb, G, xb);
    k_moe_gemm<<<dim3(DIM / BN, TOK / BM, 2), dim3(256), 0, stream>>>(xb, wt, G, out, P);
    k_reduce<<<dim3(TOK * DIM / 1024), dim3(256), 0, stream>>>(out, P);
}